// Round 5
// baseline (126.082 us; speedup 1.0000x reference)
//
#include <hip/hip_runtime.h>
#include <math.h>

#define N 8192
#define D 64

typedef short bf16x8 __attribute__((ext_vector_type(8)));
typedef float f32x4 __attribute__((ext_vector_type(4)));

__device__ __forceinline__ void gload_lds16(const void* g, void* l) {
    __builtin_amdgcn_global_load_lds(
        (const __attribute__((address_space(1))) void*)g,
        (__attribute__((address_space(3))) void*)l, 16, 0, 0);
}

__global__ void init_accs(float* accs) {
    if (threadIdx.x < 6) accs[threadIdx.x] = 0.0f;
}

// Convert fp32 -> bf16 of (sqrt(log2e)*x); nscl[i] = 0.5*||bf16(s*x)||^2 = log2e*||x||^2/2.
// MFMA on scaled inputs gives log2e*(a.b); exp(-(na+nb-2ab)/2) = exp2(ab' - na' - nb').
__global__ __launch_bounds__(256) void convert_norm(
        const float* __restrict__ X, const float* __restrict__ Y,
        const float* __restrict__ Z,
        unsigned short* __restrict__ bmat, float* __restrict__ nscl) {
    int wid  = blockIdx.x * 4 + (threadIdx.x >> 6);
    int lane = threadIdx.x & 63;
    int mat  = wid >> 13;
    int row  = wid & 8191;
    const float* src = (mat == 0) ? X : (mat == 1 ? Y : Z);
    float v = src[row * D + lane] * 1.2011224087864498f;  // sqrt(log2(e))
    unsigned int bits = __builtin_bit_cast(unsigned int, v);
    unsigned short us = (unsigned short)((bits + 0x7FFFu + ((bits >> 16) & 1u)) >> 16);
    float f = __builtin_bit_cast(float, (unsigned int)us << 16);
    bmat[(size_t)mat * (N * D) + row * D + lane] = us;
    float sq = f * f;
    #pragma unroll
    for (int off = 32; off; off >>= 1) sq += __shfl_xor(sq, off);
    if (lane == 0) nscl[mat * N + row] = sq * 0.5f;
}

// Block: 64 rows x 4096 cols of one pair; 32 iters of 128 cols.
// Wave w owns a PRIVATE 32-col slice per iter (64 rows x 32 cols output,
// 4 mt-tiles x 2 nt-tiles of 16x16x32 MFMA). B staged per-wave via
// global_load_lds into private double-buffered LDS (XOR swizzle), synced by
// counted vmcnt(4) only — NO barriers anywhere. Negligible tiles (all
// acc < -40, i.e. every term < 2^-40) skip the exp epilogue entirely.
__global__ __launch_bounds__(256, 4) void gram_kernel(
        const unsigned short* __restrict__ bmat,
        const float* __restrict__ nscl,
        float* __restrict__ accs) {
    const int PA[6] = {0, 2, 0, 0, 1, 1};  // X,Z,X,X,Y,Y
    const int PB[6] = {0, 2, 2, 1, 1, 2};  // X,Z,Z,Y,Y,Z
    int p  = blockIdx.y;
    int bx = blockIdx.x;          // 0..255
    int ti = bx >> 1;             // row strip (64 rows)
    int tc = bx & 1;              // col half (4096 cols)

    const unsigned short* A = bmat + (size_t)PA[p] * (N * D);
    const unsigned short* B = bmat + (size_t)PB[p] * (N * D);
    const float* ca = nscl + PA[p] * N;
    const float* cb = nscl + PB[p] * N;

    int tid = threadIdx.x;
    int w = tid >> 6, lane = tid & 63;
    int rowBase = ti * 64;
    int r = lane & 15, q = lane >> 4, r7 = lane & 7;

    __shared__ __align__(128) char lds[4][8192];   // per-wave 2 x 4KB
    char* ldsW = lds[w];

    // Staging: wave's 32-col tile = 4 KB contiguous in global.
    // Inverse-swizzled source granule: i*1024 + (l>>3)*128 + (((l&7)^(l>>3))<<4)
    int laneoff = ((lane >> 3) << 7) + ((r7 ^ (lane >> 3)) << 4);
    int colW = tc * 4096 + w * 32;
    const char* gB = (const char*)B + (size_t)colW * 128;

    // ds_read byte offsets (within 4KB buf): col=(nt*16+r), slot=(kc*4+q)^r7
    int offK0 = r * 128 + ((q ^ r7) << 4);
    int offK1 = r * 128 + (((4 + q) ^ r7) << 4);

    // Prologue: stage tile 0 into buf 0
    #pragma unroll
    for (int i = 0; i < 4; ++i)
        gload_lds16(gB + i * 1024 + laneoff, ldsW + i * 1024);

    // Loop-invariant A fragments (4 row tiles) and negated row-norm constants
    bf16x8 afrag[4][2];
    #pragma unroll
    for (int mt = 0; mt < 4; ++mt)
        #pragma unroll
        for (int kc = 0; kc < 2; ++kc)
            afrag[mt][kc] = *reinterpret_cast<const bf16x8*>(
                A + (size_t)(rowBase + mt * 16 + r) * D + kc * 32 + q * 8);
    f32x4 ncam[4];
    #pragma unroll
    for (int mt = 0; mt < 4; ++mt)
        #pragma unroll
        for (int e = 0; e < 4; ++e)
            ncam[mt][e] = -ca[rowBase + mt * 16 + q * 4 + e];

    const float* cbp = cb + colW + r;

    f32x4 lsum = (f32x4)0.0f;

    #pragma unroll 2
    for (int t = 0; t < 32; ++t) {
        int buf = t & 1;
        // stage tile t+1 into other buffer (clamped: last iter restages t=31)
        int tn = (t < 31) ? (t + 1) : 31;
        const char* gs = gB + (size_t)tn * 16384 + laneoff;
        char* ld = ldsW + (buf ^ 1) * 4096;
        #pragma unroll
        for (int i = 0; i < 4; ++i)
            gload_lds16(gs + i * 1024, ld + i * 1024);

        float cb0 = cbp[0], cb1 = cbp[16];

        // wait: tile t landed (tile t+1's 4 loads still in flight)
        asm volatile("s_waitcnt vmcnt(4)" ::: "memory");

        const char* lb = ldsW + buf * 4096;
        bf16x8 bfrag[2][2];
        bfrag[0][0] = *reinterpret_cast<const bf16x8*>(lb + offK0);
        bfrag[0][1] = *reinterpret_cast<const bf16x8*>(lb + offK1);
        bfrag[1][0] = *reinterpret_cast<const bf16x8*>(lb + 2048 + offK0);
        bfrag[1][1] = *reinterpret_cast<const bf16x8*>(lb + 2048 + offK1);

        // C-init carries the norm bias: acc = -(na + nb); result = log2(term)
        f32x4 acc[4][2];
        #pragma unroll
        for (int mt = 0; mt < 4; ++mt) {
            acc[mt][0] = ncam[mt] - cb0;
            acc[mt][1] = ncam[mt] - cb1;
        }
        #pragma unroll
        for (int kc = 0; kc < 2; ++kc)
            #pragma unroll
            for (int mt = 0; mt < 4; ++mt)
                #pragma unroll
                for (int nt = 0; nt < 2; ++nt)
                    acc[mt][nt] = __builtin_amdgcn_mfma_f32_16x16x32_bf16(
                        afrag[mt][kc], bfrag[nt][kc], acc[mt][nt], 0, 0, 0);

        // Negligible-tile skip: every term < 2^-40 -> contributes < 1e-12 total
        f32x4 vm = acc[0][0];
        #pragma unroll
        for (int mt = 0; mt < 4; ++mt)
            #pragma unroll
            for (int nt = 0; nt < 2; ++nt)
                if (mt | nt)
                    #pragma unroll
                    for (int e = 0; e < 4; ++e)
                        vm[e] = fmaxf(vm[e], acc[mt][nt][e]);
        float m = fmaxf(fmaxf(vm[0], vm[1]), fmaxf(vm[2], vm[3]));

        if (__any(m > -40.0f)) {
            #pragma unroll
            for (int mt = 0; mt < 4; ++mt) {
                #pragma unroll
                for (int nt = 0; nt < 2; ++nt) {
                    f32x4 ex;
                    #pragma unroll
                    for (int e = 0; e < 4; ++e)
                        ex[e] = __builtin_amdgcn_exp2f(acc[mt][nt][e]);
                    lsum += ex;
                }
            }
        }

        cbp += 128;
    }

    float ls = lsum[0] + lsum[1] + lsum[2] + lsum[3];
    #pragma unroll
    for (int off = 32; off; off >>= 1) ls += __shfl_xor(ls, off);
    if (lane == 0) atomicAdd(&accs[p], ls);
}

__global__ void finalize_kernel(const float* __restrict__ accs,
                                float* __restrict__ out) {
    double inv = 1.0 / (8192.0 * 8192.0 * 3.5449077018110318);
    double mxx = accs[0] * inv, mzz = accs[1] * inv, mxz = accs[2] * inv;
    double mxy = accs[3] * inv, myy = accs[4] * inv, myz = accs[5] * inv;
    double r1 = log(3.0 * sqrt(mxx * mzz + 1e-5) / (mxz + 1e-5));
    double r2 = log(3.0 * sqrt(myy * mzz + 1e-5) / (myz + 1e-5));
    double r3 = log(3.0 * sqrt(mxx * myy + 1e-5) / (mxy + 1e-5));
    out[0] = (float)(10.0 * r1 + r2 + 10.0 * r3);
}

extern "C" void kernel_launch(void* const* d_in, const int* in_sizes, int n_in,
                              void* d_out, int out_size, void* d_ws, size_t ws_size,
                              hipStream_t stream) {
    const float* X = (const float*)d_in[0];
    const float* Y = (const float*)d_in[1];
    const float* Z = (const float*)d_in[2];
    char* ws = (char*)d_ws;
    unsigned short* bmat = (unsigned short*)ws;                       // 3 MB
    float* nscl = (float*)(ws + (size_t)3 * N * D * 2);               // 3*8192 f32
    float* accs = (float*)(ws + (size_t)3 * N * D * 2 + (size_t)3 * N * 4);
    float* out = (float*)d_out;

    hipLaunchKernelGGL(init_accs, dim3(1), dim3(64), 0, stream, accs);
    hipLaunchKernelGGL(convert_norm, dim3(3 * N / 4), dim3(256), 0, stream,
                       X, Y, Z, bmat, nscl);
    hipLaunchKernelGGL(gram_kernel, dim3(256, 6), dim3(256), 0, stream,
                       bmat, nscl, accs);
    hipLaunchKernelGGL(finalize_kernel, dim3(1), dim3(1), 0, stream, accs, out);
}

// Round 6
// 83.755 us; speedup vs baseline: 1.5054x; 1.5054x over previous
//
#include <hip/hip_runtime.h>
#include <math.h>

#define N 8192
#define D 64

typedef short bf16x8 __attribute__((ext_vector_type(8)));
typedef float f32x4 __attribute__((ext_vector_type(4)));

__device__ __forceinline__ void gload_lds16(const void* g, void* l) {
    __builtin_amdgcn_global_load_lds(
        (const __attribute__((address_space(1))) void*)g,
        (__attribute__((address_space(3))) void*)l, 16, 0, 0);
}

__global__ void init_accs(float* accs) {
    if (threadIdx.x < 6) accs[threadIdx.x] = 0.0f;
}

// Convert fp32 -> bf16 of (sqrt(log2e)*x); nscl[i] = 0.5*||bf16(s*x)||^2 = log2e*||x||^2/2.
// MFMA on scaled inputs gives log2e*(a.b); exp(-(na+nb-2ab)/2) = exp2(ab' - na' - nb').
__global__ __launch_bounds__(256) void convert_norm(
        const float* __restrict__ X, const float* __restrict__ Y,
        const float* __restrict__ Z,
        unsigned short* __restrict__ bmat, float* __restrict__ nscl) {
    int wid  = blockIdx.x * 4 + (threadIdx.x >> 6);
    int lane = threadIdx.x & 63;
    int mat  = wid >> 13;
    int row  = wid & 8191;
    const float* src = (mat == 0) ? X : (mat == 1 ? Y : Z);
    float v = src[row * D + lane] * 1.2011224087864498f;  // sqrt(log2(e))
    unsigned int bits = __builtin_bit_cast(unsigned int, v);
    unsigned short us = (unsigned short)((bits + 0x7FFFu + ((bits >> 16) & 1u)) >> 16);
    float f = __builtin_bit_cast(float, (unsigned int)us << 16);
    bmat[(size_t)mat * (N * D) + row * D + lane] = us;
    float sq = f * f;
    #pragma unroll
    for (int off = 32; off; off >>= 1) sq += __shfl_xor(sq, off);
    if (lane == 0) nscl[mat * N + row] = sq * 0.5f;
}

// Block: 64 rows x 4096 cols of one pair; 64 iters of 64-col tiles (8 KB).
// Cooperative staging (each wave stages its 2 KB sub-region) into TRIPLE-
// buffered LDS with XOR swizzle. Sync per iter: s_waitcnt vmcnt(2) + raw
// s_barrier — loads for tile t+1 stay in flight across the barrier (no
// vmcnt(0) drain). Negligible tiles (all acc < -40) skip the exp epilogue.
__global__ __launch_bounds__(256, 6) void gram_kernel(
        const unsigned short* __restrict__ bmat,
        const float* __restrict__ nscl,
        float* __restrict__ accs) {
    const int PA[6] = {0, 2, 0, 0, 1, 1};  // X,Z,X,X,Y,Y
    const int PB[6] = {0, 2, 2, 1, 1, 2};  // X,Z,Z,Y,Y,Z
    int p  = blockIdx.y;
    int bx = blockIdx.x;          // 0..255
    int ti = bx >> 1;             // row strip (64 rows)
    int tc = bx & 1;              // col half (4096 cols)

    const unsigned short* A = bmat + (size_t)PA[p] * (N * D);
    const unsigned short* B = bmat + (size_t)PB[p] * (N * D);
    const float* ca = nscl + PA[p] * N;
    const float* cb = nscl + PB[p] * N;

    int tid = threadIdx.x;
    int w = tid >> 6, lane = tid & 63;
    int wr = w >> 1, wc = w & 1;
    int rowBase = ti * 64 + wr * 32;
    int r = lane & 15, q = lane >> 4, r7 = lane & 7;

    __shared__ __align__(128) char lds[3 * 8192];   // triple-buffered 8 KB tiles
    __shared__ float wsum[4];

    // Staging: tile = 64 cols x 128 B contiguous; wave w stages sub-region.
    // Inverse-swizzled source; LDS dest linear (granule l*16).
    int sub = w * 2048;
    int laneoff = ((lane >> 3) << 7) + ((r7 ^ (lane >> 3)) << 4);
    const char* gB = (const char*)(B + (size_t)(tc * 4096) * D);

    // Swizzled ds_read offsets: phys(col,slot) holds global slot^(col&7)
    int off0 = wc * 4096 + r * 128 + ((q ^ r7) << 4);        // kc=0
    int off1 = wc * 4096 + r * 128 + (((4 + q) ^ r7) << 4);  // kc=1

    // Prologue: stage tiles 0,1 into bufs 0,1 (4 loads/wave outstanding)
    {
        const char* g0 = gB + sub + laneoff;
        gload_lds16(g0,        lds + sub);
        gload_lds16(g0 + 1024, lds + sub + 1024);
        const char* g1 = gB + 8192 + sub + laneoff;
        gload_lds16(g1,        lds + 8192 + sub);
        gload_lds16(g1 + 1024, lds + 8192 + sub + 1024);
    }

    // Loop-invariant A fragments and negated row-norm constants
    bf16x8 afrag[2][2];
    #pragma unroll
    for (int mt = 0; mt < 2; ++mt)
        #pragma unroll
        for (int kc = 0; kc < 2; ++kc)
            afrag[mt][kc] = *reinterpret_cast<const bf16x8*>(
                A + (size_t)(rowBase + mt * 16 + r) * D + kc * 32 + q * 8);
    f32x4 ncam[2];
    #pragma unroll
    for (int mt = 0; mt < 2; ++mt)
        #pragma unroll
        for (int e = 0; e < 4; ++e)
            ncam[mt][e] = -ca[rowBase + mt * 16 + q * 4 + e];

    const float* cbp = cb + tc * 4096 + wc * 32 + r;

    f32x4 lsum = (f32x4)0.0f;
    unsigned rb = 0;   // read-buffer byte offset: 0 / 8192 / 16384

    for (int t = 0; t < 64; ++t) {
        // Tile t landed when all but the newest 2 VMEM events (iter t-1's
        // stage pair) retired; barrier publishes it block-wide.
        asm volatile("s_waitcnt vmcnt(2)" ::: "memory");
        __builtin_amdgcn_s_barrier();
        asm volatile("" ::: "memory");

        // cb loads FIRST (so they retire before this iter's stage loads)
        float cb0 = cbp[0], cb1 = cbp[16];

        // Stage tile min(t+2,63) into buffer (t+2)%3 (clamped re-stage keeps
        // the vmcnt ledger uniform; its buffer is never read again).
        unsigned sb = rb + 16384; if (sb >= 24576) sb -= 24576;
        int tn = (t + 2 <= 63) ? (t + 2) : 63;
        const char* gs = gB + (size_t)tn * 8192 + sub + laneoff;
        gload_lds16(gs,        lds + sb + sub);
        gload_lds16(gs + 1024, lds + sb + sub + 1024);

        const char* lb = lds + rb;
        bf16x8 bfrag[2][2];
        bfrag[0][0] = *reinterpret_cast<const bf16x8*>(lb + off0);
        bfrag[0][1] = *reinterpret_cast<const bf16x8*>(lb + off1);
        bfrag[1][0] = *reinterpret_cast<const bf16x8*>(lb + 2048 + off0);
        bfrag[1][1] = *reinterpret_cast<const bf16x8*>(lb + 2048 + off1);

        // C-init carries the norm bias: acc = -(na + nb); result = log2(term)
        f32x4 acc[2][2];
        acc[0][0] = ncam[0] - cb0; acc[0][1] = ncam[0] - cb1;
        acc[1][0] = ncam[1] - cb0; acc[1][1] = ncam[1] - cb1;

        #pragma unroll
        for (int kc = 0; kc < 2; ++kc)
            #pragma unroll
            for (int mt = 0; mt < 2; ++mt)
                #pragma unroll
                for (int nt = 0; nt < 2; ++nt)
                    acc[mt][nt] = __builtin_amdgcn_mfma_f32_16x16x32_bf16(
                        afrag[mt][kc], bfrag[nt][kc], acc[mt][nt], 0, 0, 0);

        // Negligible-tile skip: every term < 2^-40 -> total error < 1e-12
        f32x4 vm = acc[0][0];
        #pragma unroll
        for (int mt = 0; mt < 2; ++mt)
            #pragma unroll
            for (int nt = 0; nt < 2; ++nt)
                if (mt | nt)
                    #pragma unroll
                    for (int e = 0; e < 4; ++e)
                        vm[e] = fmaxf(vm[e], acc[mt][nt][e]);
        float m = fmaxf(fmaxf(vm[0], vm[1]), fmaxf(vm[2], vm[3]));

        if (__any(m > -40.0f)) {
            #pragma unroll
            for (int mt = 0; mt < 2; ++mt) {
                #pragma unroll
                for (int nt = 0; nt < 2; ++nt) {
                    f32x4 ex;
                    #pragma unroll
                    for (int e = 0; e < 4; ++e)
                        ex[e] = __builtin_amdgcn_exp2f(acc[mt][nt][e]);
                    lsum += ex;
                }
            }
        }

        cbp += 64;
        rb += 8192; if (rb >= 24576) rb = 0;
    }

    float ls = lsum[0] + lsum[1] + lsum[2] + lsum[3];
    #pragma unroll
    for (int off = 32; off; off >>= 1) ls += __shfl_xor(ls, off);
    if (lane == 0) wsum[w] = ls;
    __syncthreads();
    if (tid == 0)
        atomicAdd(&accs[p], wsum[0] + wsum[1] + wsum[2] + wsum[3]);
}

__global__ void finalize_kernel(const float* __restrict__ accs,
                                float* __restrict__ out) {
    double inv = 1.0 / (8192.0 * 8192.0 * 3.5449077018110318);
    double mxx = accs[0] * inv, mzz = accs[1] * inv, mxz = accs[2] * inv;
    double mxy = accs[3] * inv, myy = accs[4] * inv, myz = accs[5] * inv;
    double r1 = log(3.0 * sqrt(mxx * mzz + 1e-5) / (mxz + 1e-5));
    double r2 = log(3.0 * sqrt(myy * mzz + 1e-5) / (myz + 1e-5));
    double r3 = log(3.0 * sqrt(mxx * myy + 1e-5) / (mxy + 1e-5));
    out[0] = (float)(10.0 * r1 + r2 + 10.0 * r3);
}

extern "C" void kernel_launch(void* const* d_in, const int* in_sizes, int n_in,
                              void* d_out, int out_size, void* d_ws, size_t ws_size,
                              hipStream_t stream) {
    const float* X = (const float*)d_in[0];
    const float* Y = (const float*)d_in[1];
    const float* Z = (const float*)d_in[2];
    char* ws = (char*)d_ws;
    unsigned short* bmat = (unsigned short*)ws;                       // 3 MB
    float* nscl = (float*)(ws + (size_t)3 * N * D * 2);               // 3*8192 f32
    float* accs = (float*)(ws + (size_t)3 * N * D * 2 + (size_t)3 * N * 4);
    float* out = (float*)d_out;

    hipLaunchKernelGGL(init_accs, dim3(1), dim3(64), 0, stream, accs);
    hipLaunchKernelGGL(convert_norm, dim3(3 * N / 4), dim3(256), 0, stream,
                       X, Y, Z, bmat, nscl);
    hipLaunchKernelGGL(gram_kernel, dim3(256, 6), dim3(256), 0, stream,
                       bmat, nscl, accs);
    hipLaunchKernelGGL(finalize_kernel, dim3(1), dim3(1), 0, stream, accs, out);
}